// Round 2
// baseline (34.159 us; speedup 1.0000x reference)
//
#include <hip/hip_runtime.h>

// out[b] = (2.0*0.5) * dot(x[b,:], colsum(weight))   — memory-bound, 128 MiB reads.
// K1: partial column sums of W, 2048 blocks (full occupancy).
// K2: reduce 512 chunk-partials -> wsum[4096], 32 blocks.
// K3: per-row dot of x against wsum, 4096 blocks.

#define BATCH 4096
#define ISZ   4096
#define HSZ   4096
#define COL4  (ISZ / 4)        // 1024 float4 columns
#define RC    512              // row chunks
#define ROWS_PER_CHUNK (HSZ / RC)   // 8
#define SCALE 1.0f

// K1: grid = (4, RC) = 2048 blocks, block = 256. Each block: 8 rows x 4KB col-group.
__global__ __launch_bounds__(256) void colsum_partial(
    const float* __restrict__ w, float* __restrict__ part) {
    const int col4  = blockIdx.x * 256 + threadIdx.x;   // float4 column
    const int chunk = blockIdx.y;
    const float4* w4 = (const float4*)w;
    const size_t row0 = (size_t)chunk * ROWS_PER_CHUNK;
    float4 acc = make_float4(0.f, 0.f, 0.f, 0.f);
    #pragma unroll
    for (int r = 0; r < ROWS_PER_CHUNK; ++r) {          // 8 independent loads in flight
        float4 v = w4[(row0 + r) * COL4 + col4];
        acc.x += v.x; acc.y += v.y; acc.z += v.z; acc.w += v.w;
    }
    ((float4*)part)[(size_t)chunk * COL4 + col4] = acc;
}

// K2: grid = 32, block = 256. Block j covers float4 cols [j*32, j*32+32).
// Thread t: col = j*32 + (t&31), group g = t>>5 sums chunks [g*64, g*64+64).
// LDS tree across the 8 groups.
__global__ __launch_bounds__(256) void colsum_finish(
    const float* __restrict__ part, float* __restrict__ wsum) {
    __shared__ float4 buf[256];
    const int t    = threadIdx.x;
    const int col4 = blockIdx.x * 32 + (t & 31);
    const int g    = t >> 5;
    const float4* p4 = (const float4*)part;
    float4 acc = make_float4(0.f, 0.f, 0.f, 0.f);
    #pragma unroll 8
    for (int c = g * 64; c < g * 64 + 64; ++c) {
        float4 v = p4[(size_t)c * COL4 + col4];
        acc.x += v.x; acc.y += v.y; acc.z += v.z; acc.w += v.w;
    }
    buf[t] = acc;
    __syncthreads();
    #pragma unroll
    for (int s = 4; s >= 1; s >>= 1) {
        if (g < s) {
            float4 o = buf[t + 32 * s];
            acc.x += o.x; acc.y += o.y; acc.z += o.z; acc.w += o.w;
            buf[t] = acc;
        }
        __syncthreads();
    }
    if (g == 0) ((float4*)wsum)[col4] = buf[t];
}

// K3: grid = BATCH, block = 256. out[b] = SCALE * dot(x[b], wsum).
__global__ __launch_bounds__(256) void rowdot(
    const float* __restrict__ x, const float* __restrict__ wsum,
    float* __restrict__ out) {
    const int b   = blockIdx.x;
    const int tid = threadIdx.x;
    const float4* x4 = (const float4*)(x + (size_t)b * ISZ);
    const float4* s4 = (const float4*)wsum;
    float acc = 0.f;
    #pragma unroll
    for (int it = 0; it < COL4 / 256; ++it) {
        const int idx = it * 256 + tid;
        float4 xv = x4[idx];
        float4 sv = s4[idx];
        acc += xv.x * sv.x + xv.y * sv.y + xv.z * sv.z + xv.w * sv.w;
    }
    #pragma unroll
    for (int off = 32; off > 0; off >>= 1)
        acc += __shfl_down(acc, off, 64);
    __shared__ float red[4];
    const int wave = tid >> 6;
    if ((tid & 63) == 0) red[wave] = acc;
    __syncthreads();
    if (tid == 0) out[b] = SCALE * (red[0] + red[1] + red[2] + red[3]);
}

extern "C" void kernel_launch(void* const* d_in, const int* in_sizes, int n_in,
                              void* d_out, int out_size, void* d_ws, size_t ws_size,
                              hipStream_t stream) {
    const float* x = (const float*)d_in[0];   // [BATCH, ISZ]
    const float* w = (const float*)d_in[1];   // [HSZ, ISZ]
    float* out = (float*)d_out;

    float* part = (float*)d_ws;                        // RC * ISZ f32 = 8 MiB
    float* wsum = (float*)d_ws + (size_t)RC * ISZ;     // 16 KiB

    colsum_partial<<<dim3(4, RC), 256, 0, stream>>>(w, part);
    colsum_finish<<<dim3(32), 256, 0, stream>>>(part, wsum);
    rowdot<<<dim3(BATCH), 256, 0, stream>>>(x, wsum, out);
}